// Round 11
// baseline (195.045 us; speedup 1.0000x reference)
//
#include <hip/hip_runtime.h>

// SelfAttention (B=4, C=256, H=W=64): fused projections + merged-wave flash.
// Round 14: r13 (93us, confirmed request-rate theory: MfmaUtil 15->27, -43%)
// still stalls ~32% of issue slots. Remaining exposure: V(kt) was loaded
// INSIDE the PV blocks right before its consuming MFMAs (r13's live-range
// trick) -> 2x ~300cy load->use round trips per tile at ~1.5 resident
// waves/SIMD. This round (one variable): V pipelined ONE FULL TILE ahead in
// persistent vf[4][4] (64 VGPR): issue 16 loads after PV(kt), consume after
// QK+softmax+pack(kt+1) (~400-500cy cover). Raw s_barrier doesn't drain
// vmcnt -> loads fly across the tile boundary. Peak VGPR ~200 < 256 budget
// of (256,2); spill canary = WRITE_SIZE (must stay 33MB).
// Everything else = r13: fragment-packed K/V, phase-lock barrier, fixed-M
// exp2 softmax, split-K x4, zero LDS, normalized f16 partials, 4-way combine.

#define B_ 4
#define C_ 256
#define N_ 4096
#define CQK 32
#define LOG2E 1.44269504088896340736f

typedef __attribute__((ext_vector_type(8))) short short8;
typedef __attribute__((ext_vector_type(4))) short short4v;
typedef __attribute__((ext_vector_type(4))) unsigned int uint4v;
typedef __attribute__((ext_vector_type(16))) float f32x16;
typedef __attribute__((ext_vector_type(4))) float f32x4;

__device__ __forceinline__ unsigned short f2bf(float f) {
  unsigned int u = __builtin_bit_cast(unsigned int, f);
  u = (u + 0x7fffu + ((u >> 16) & 1u)) >> 16;  // RNE
  return (unsigned short)u;
}
__device__ __forceinline__ float bf2f(unsigned short s) {
  unsigned int u = ((unsigned int)s) << 16;
  return __builtin_bit_cast(float, u);
}
__device__ __forceinline__ short f32tof16(float f) {
  const _Float16 hf = (_Float16)f;
  return __builtin_bit_cast(short, hf);
}
// pack two f32 -> two bf16 (RNE), one instruction
__device__ __forceinline__ unsigned int cvtpk(float lo, float hi) {
  unsigned int r;
  asm("v_cvt_pk_bf16_f32 %0, %1, %2" : "=v"(r) : "v"(lo), "v"(hi));
  return r;
}
__device__ __forceinline__ f32x16 mfma16(short8 a, short8 b, f32x16 c) {
  return __builtin_amdgcn_mfma_f32_32x32x16_bf16(a, b, c, 0, 0, 0);
}
// swizzled element index into bf16 LDS tiles (16B granules XORed by row)
__device__ __forceinline__ int swz64(int row, int col) {  // rows of 64 bf16
  return row * 64 + ((((col >> 3) ^ row) & 7) << 3) + (col & 7);
}

// ---------------- kernel 1: prep (x transpose+split, weight splits) ----------
__global__ __launch_bounds__(256) void k_prep(
    const float* __restrict__ x, unsigned short* __restrict__ xthi,
    unsigned short* __restrict__ xtlo,
    const float* __restrict__ Wq, const float* __restrict__ Wk,
    const float* __restrict__ Wv,
    unsigned short* __restrict__ wqh, unsigned short* __restrict__ wql,
    unsigned short* __restrict__ wkh, unsigned short* __restrict__ wkl,
    unsigned short* __restrict__ wvh, unsigned short* __restrict__ wvl) {
  __shared__ __align__(16) float tile[64 * 65];
  const int bi = blockIdx.x;
  const int t = threadIdx.x;
  if (bi < 1024) {
    const int it = bi & 63, ct = (bi >> 6) & 3, b = bi >> 8;
    const int i0 = it * 64, c0 = ct * 64;
    {
      const int i = t & 63, cb = t >> 6;
#pragma unroll
      for (int z = 0; z < 16; ++z) {
        const int c = z * 4 + cb;
        tile[i * 65 + c] = x[(b * C_ + c0 + c) * N_ + i0 + i];
      }
    }
    __syncthreads();
    {
      const int ii = t >> 2, p = t & 3;
      short8 h0, h1, l0, l1;
#pragma unroll
      for (int e = 0; e < 16; ++e) {
        const float f = tile[ii * 65 + p * 16 + e];
        const unsigned short hb = f2bf(f);
        const unsigned short lb = f2bf(f - bf2f(hb));
        if (e < 8) { h0[e] = (short)hb; l0[e] = (short)lb; }
        else       { h1[e - 8] = (short)hb; l1[e - 8] = (short)lb; }
      }
      const int base = (b * N_ + i0 + ii) * C_ + c0 + p * 16;
      *(short8*)(xthi + base) = h0;
      *(short8*)(xthi + base + 8) = h1;
      *(short8*)(xtlo + base) = l0;
      *(short8*)(xtlo + base + 8) = l1;
    }
  } else {
    const int e = (bi - 1024) * 256 + t;  // < 81920
    const float* src; unsigned short *hi, *lo; int idx;
    if (e < 8192)        { src = Wq; hi = wqh; lo = wql; idx = e; }
    else if (e < 16384)  { src = Wk; hi = wkh; lo = wkl; idx = e - 8192; }
    else                 { src = Wv; hi = wvh; lo = wvl; idx = e - 16384; }
    float f = src[idx];
    if (e < 8192) f *= LOG2E;  // log2-domain scores: fold log2(e) into Wq
    const unsigned short h = f2bf(f);
    hi[idx] = h;
    lo[idx] = f2bf(f - bf2f(h));
  }
}

// ---------------- kernel 2: fused q/k/v projection GEMM ----------------
// q written [B][N][32] hi/lo (unchanged). K and V written FRAGMENT-PACKED:
// kfr[((b*128 + j32t)*2 + kk)*64 + (jl + 32*h)]*8  holds K[j32t*32+jl][kk*16+h*8+..]
// vfr[(b*64+jt)*16384 + ct*2048 + sl*512 + (cl+32*hh)*8 + e8]
//    holds V[ct*32+cl][jt*64 + sl*16 + hh*8 + e8]
__global__ __launch_bounds__(256) void k_proj(
    const unsigned short* __restrict__ wqh, const unsigned short* __restrict__ wql,
    const unsigned short* __restrict__ wkh, const unsigned short* __restrict__ wkl,
    const unsigned short* __restrict__ wvh, const unsigned short* __restrict__ wvl,
    const unsigned short* __restrict__ xthi, const unsigned short* __restrict__ xtlo,
    const float* __restrict__ bq, const float* __restrict__ bk,
    const float* __restrict__ bv,
    unsigned short* __restrict__ qhg, unsigned short* __restrict__ qlg,
    unsigned short* __restrict__ kfrh, unsigned short* __restrict__ kfrl,
    unsigned short* __restrict__ vfr) {
  __shared__ __align__(16) char sm[33792];
  unsigned short* awh = (unsigned short*)sm;       // [64][64] W hi (swizzled)
  unsigned short* awl = awh + 4096;
  unsigned short* bxh = awl + 4096;                // [64][64] x^T hi
  unsigned short* bxl = bxh + 4096;
  float* qt = (float*)sm;                          // epilogue reuse: [64][65] f32

  const int it = blockIdx.x, ot = blockIdx.y, b = blockIdx.z;
  const int i0 = it * 64, o0 = ot * 64;
  const int t = threadIdx.x, lane = t & 63, w = t >> 6, h = lane >> 5;
  const int mb = w >> 1, nb = w & 1;
  const int srow = t >> 2, sp = t & 3;

  const int og = o0 + srow;
  const unsigned short *wh, *wl;
  if (og < 32)      { wh = wqh + og * C_;        wl = wql + og * C_; }
  else if (og < 64) { wh = wkh + (og - 32) * C_; wl = wkl + (og - 32) * C_; }
  else              { wh = wvh + (og - 64) * C_; wl = wvl + (og - 64) * C_; }
  const unsigned short* xh = xthi + (b * N_ + i0 + srow) * C_;
  const unsigned short* xl = xtlo + (b * N_ + i0 + srow) * C_;

  f32x16 acc;
#pragma unroll
  for (int e = 0; e < 16; ++e) acc[e] = 0.f;
  const int m = 32 * mb + (lane & 31);
  const int n = 32 * nb + (lane & 31);

  for (int kt = 0; kt < 4; ++kt) {
    const int cb = kt * 64 + sp * 16;
    *(short8*)&awh[swz64(srow, sp * 16)]     = *(const short8*)(wh + cb);
    *(short8*)&awh[swz64(srow, sp * 16 + 8)] = *(const short8*)(wh + cb + 8);
    *(short8*)&awl[swz64(srow, sp * 16)]     = *(const short8*)(wl + cb);
    *(short8*)&awl[swz64(srow, sp * 16 + 8)] = *(const short8*)(wl + cb + 8);
    *(short8*)&bxh[swz64(srow, sp * 16)]     = *(const short8*)(xh + cb);
    *(short8*)&bxh[swz64(srow, sp * 16 + 8)] = *(const short8*)(xh + cb + 8);
    *(short8*)&bxl[swz64(srow, sp * 16)]     = *(const short8*)(xl + cb);
    *(short8*)&bxl[swz64(srow, sp * 16 + 8)] = *(const short8*)(xl + cb + 8);
    __syncthreads();
#pragma unroll
    for (int kk = 0; kk < 4; ++kk) {
      const int kb = kk * 16 + h * 8;
      const short8 ah  = *(const short8*)&awh[swz64(m, kb)];
      const short8 al2 = *(const short8*)&awl[swz64(m, kb)];
      const short8 bh  = *(const short8*)&bxh[swz64(n, kb)];
      const short8 bl2 = *(const short8*)&bxl[swz64(n, kb)];
      acc = mfma16(ah, bh, acc);   // hi*hi
      acc = mfma16(ah, bl2, acc);  // hi*lo
      acc = mfma16(al2, bh, acc);  // lo*hi
    }
    __syncthreads();
  }

  if (ot > 0) {  // v epilogue: fragment-packed bf16 scatter store
    // thread owns (oc = o0-64+32*mb+rr, j = i0+n); it == jt, n == jl
    const int vbase = (b * 64 + it) * 16384 + (2 * (ot - 1) + mb) * 2048 +
                      (n >> 4) * 512 + 256 * ((n >> 3) & 1) + (n & 7);
#pragma unroll
    for (int e = 0; e < 16; ++e) {
      const int rr = (e & 3) + 8 * (e >> 2) + 4 * h;
      const int oc = o0 - 64 + 32 * mb + rr;
      vfr[vbase + rr * 8] = f2bf(acc[e] + bv[oc]);
    }
  } else {  // q/k epilogue: LDS transpose -> q [B][N][32]; K fragment-packed
#pragma unroll
    for (int e = 0; e < 16; ++e) {
      const int r = 32 * mb + (e & 3) + 8 * (e >> 2) + 4 * h;
      const float bias = (r < 32) ? bq[r] * LOG2E : bk[r - 32];
      qt[r * 65 + n] = acc[e] + bias;
    }
    __syncthreads();
    const int ii = t >> 2;
    short8 hv0, hv1, lv0, lv1;
#pragma unroll
    for (int e = 0; e < 16; ++e) {
      const float f = qt[(sp * 16 + e) * 65 + ii];
      const unsigned short hb = f2bf(f);
      const unsigned short lb = f2bf(f - bf2f(hb));
      if (e < 8) { hv0[e] = (short)hb; lv0[e] = (short)lb; }
      else       { hv1[e - 8] = (short)hb; lv1[e - 8] = (short)lb; }
    }
    if (sp < 2) {
      const int base = (b * N_ + i0 + ii) * CQK + sp * 16;
      *(short8*)(qhg + base) = hv0; *(short8*)(qhg + base + 8) = hv1;
      *(short8*)(qlg + base) = lv0; *(short8*)(qlg + base + 8) = lv1;
    } else {
      // key = i0+ii; hv0 = cqk[kk*16..+8] (h=0), hv1 = cqk[kk*16+8..] (h=1)
      const int key = i0 + ii;
      const int j32t = key >> 5, jl = key & 31;
      const int kk = sp - 2;
      const size_t kb2 = ((size_t)(b * 128 + j32t) * 2 + kk) * 512;
      *(short8*)(kfrh + kb2 + jl * 8) = hv0;
      *(short8*)(kfrh + kb2 + (jl + 32) * 8) = hv1;
      *(short8*)(kfrl + kb2 + jl * 8) = lv0;
      *(short8*)(kfrl + kb2 + (jl + 32) * 8) = lv1;
    }
  }
}

// ---------------- kernel 3: merged-wave flash, fixed-M, packed + pipelined --
// 1024 blocks x 256 thr (4 waves). xs = blk&7 = b*2+s_hi (XCD-pinned);
// gl = blk>>3: s = (xs&1)*2 + (gl&1); widx = (gl>>1)*4+w: qw=widx>>1, ch=widx&1.
// Wave = 32 q-rows x 128 channels, keys [s*1024,+1024) in 16 tiles of 64.
// Pipeline: V(kt+1) issued after PV(kt) into persistent vf[4][4]; consumed
// after QK+softmax+pack(kt+1) (~400-500cy cover). K(kt+1) prefetched under
// softmax. Raw s_barrier per tile phase-locks waves (L1 stream dedup) and
// does NOT drain vmcnt. Fixed-M exp2 softmax; in-register P redistribution;
// normalized f16 partials + l. Opart: [wave 4096][slot 8][lane 64][8 f16].
__global__ __launch_bounds__(256, 2) void k_flash(
    const unsigned short* __restrict__ qhg, const unsigned short* __restrict__ qlg,
    const unsigned short* __restrict__ kfrh, const unsigned short* __restrict__ kfrl,
    const unsigned short* __restrict__ vfr,
    unsigned short* __restrict__ Opart, float* __restrict__ lpart) {
  const int blk = blockIdx.x;
  const int xs = blk & 7;          // XCD-pinned (b, s_hi)
  const int b = xs >> 1;
  const int gl = blk >> 3;         // 0..127
  const int s = (xs & 1) * 2 + (gl & 1);
  const int t = threadIdx.x, lane = t & 63, w = t >> 6, h = lane >> 5;
  const int l31 = lane & 31;
  const int widx = (gl >> 1) * 4 + w;  // 0..255
  const int qw = widx >> 1, ch = widx & 1;
  const int srow = qw * 32 + l31;  // q row of this lane (QK layout)

  // Q fragments (persistent): B-operand for QK, lane = q
  short8 qfh[2], qfl[2];
  {
    const unsigned short* qph = qhg + (size_t)(b * N_ + srow) * CQK + h * 8;
    const unsigned short* qpl = qlg + (size_t)(b * N_ + srow) * CQK + h * 8;
#pragma unroll
    for (int kk = 0; kk < 2; ++kk) {
      qfh[kk] = *(const short8*)(qph + kk * 16);
      qfl[kk] = *(const short8*)(qpl + kk * 16);
    }
  }
  // K fragments: packed blocks of 512 shorts, local j32t = tau*2+jt
  const unsigned short* kbh = kfrh + (size_t)(b * 128 + s * 32) * 1024 + lane * 8;
  const unsigned short* kbl = kfrl + (size_t)(b * 128 + s * 32) * 1024 + lane * 8;
  short8 kfh[2][2], kfl[2][2];
  auto loadK = [&](int tau) {
#pragma unroll
    for (int jt = 0; jt < 2; ++jt)
#pragma unroll
      for (int kk = 0; kk < 2; ++kk) {
        const int off = ((tau * 2 + jt) * 2 + kk) * 512;
        kfh[jt][kk] = *(const short8*)(kbh + off);
        kfl[jt][kk] = *(const short8*)(kbl + off);
      }
  };
  // V fragments: packed; per (tile, ct, sl) a contiguous 1KB wave-load.
  // Persistent vf = one full tile, pipelined one tile ahead.
  const unsigned short* vbase =
      vfr + (size_t)(b * 64 + s * 16) * 16384 + (ch * 4) * 2048 + lane * 8;
  short8 vf[4][4];
  auto loadV = [&](int kt2) {
#pragma unroll
    for (int ct = 0; ct < 4; ++ct)
#pragma unroll
      for (int sl = 0; sl < 4; ++sl)
        vf[ct][sl] = *(const short8*)(vbase + kt2 * 16384 + ct * 2048 + sl * 512);
  };
  loadV(0);
  loadK(0);

  f32x16 acc0, acc1, acc2, acc3;
#pragma unroll
  for (int e = 0; e < 16; ++e) {
    acc0[e] = 0.f; acc1[e] = 0.f; acc2[e] = 0.f; acc3[e] = 0.f;
  }
  float l_run = 0.f;  // own half (32 j's per tile); partner-merged at end

  for (int kt = 0; kt < 16; ++kt) {
    __builtin_amdgcn_s_barrier();  // phase-lock 4 waves -> L1 stream dedup
    // QK: S^T tiles, lane = q, regs = j pattern (e&3)+8*(e>>2)+4h
    f32x16 s0, s1;
#pragma unroll
    for (int e = 0; e < 16; ++e) { s0[e] = 0.f; s1[e] = 0.f; }
    __builtin_amdgcn_s_setprio(1);
#pragma unroll
    for (int kk = 0; kk < 2; ++kk) {
      s0 = mfma16(kfh[0][kk], qfh[kk], s0);
      s0 = mfma16(kfh[0][kk], qfl[kk], s0);
      s0 = mfma16(kfl[0][kk], qfh[kk], s0);
      s1 = mfma16(kfh[1][kk], qfh[kk], s1);
      s1 = mfma16(kfh[1][kk], qfl[kk], s1);
      s1 = mfma16(kfl[1][kk], qfh[kk], s1);
    }
    __builtin_amdgcn_s_setprio(0);
    if (kt + 1 < 16) loadK(kt + 1);  // prefetch next K under exp2+PV
    // ---- fixed-M softmax: P = exp2(S) (log2 domain), no max chain ----
#pragma unroll
    for (int e = 0; e < 16; ++e) s0[e] = __builtin_exp2f(s0[e]);
#pragma unroll
    for (int e = 0; e < 16; ++e) s1[e] = __builtin_exp2f(s1[e]);
    {
      float t8[8];
#pragma unroll
      for (int i2 = 0; i2 < 4; ++i2) {
        t8[i2] = (s0[4 * i2] + s0[4 * i2 + 1]) + (s0[4 * i2 + 2] + s0[4 * i2 + 3]);
        t8[4 + i2] = (s1[4 * i2] + s1[4 * i2 + 1]) + (s1[4 * i2 + 2] + s1[4 * i2 + 3]);
      }
      l_run += ((t8[0] + t8[1]) + (t8[2] + t8[3])) +
               ((t8[4] + t8[5]) + (t8[6] + t8[7]));
    }
    // ---- in-register P redistribution -> PV A-frags (verified layout) ----
    short8 pa0, pa1, pa2, pa3;
    {
      unsigned int w01 = cvtpk(s0[0], s0[1]),  w23 = cvtpk(s0[2], s0[3]);
      unsigned int w45 = cvtpk(s0[4], s0[5]),  w67 = cvtpk(s0[6], s0[7]);
      unsigned int w89 = cvtpk(s0[8], s0[9]),  wab = cvtpk(s0[10], s0[11]);
      unsigned int wcd = cvtpk(s0[12], s0[13]), wef = cvtpk(s0[14], s0[15]);
      unsigned int t01 = (unsigned)__shfl_xor((int)w01, 32);
      unsigned int t23 = (unsigned)__shfl_xor((int)w23, 32);
      unsigned int t45 = (unsigned)__shfl_xor((int)w45, 32);
      unsigned int t67 = (unsigned)__shfl_xor((int)w67, 32);
      unsigned int t89 = (unsigned)__shfl_xor((int)w89, 32);
      unsigned int tab = (unsigned)__shfl_xor((int)wab, 32);
      unsigned int tcd = (unsigned)__shfl_xor((int)wcd, 32);
      unsigned int tef = (unsigned)__shfl_xor((int)wef, 32);
      uint4v uA, uB;
      uA[0] = h ? t45 : w01;  uA[1] = h ? t67 : w23;
      uA[2] = h ? w45 : t01;  uA[3] = h ? w67 : t23;
      uB[0] = h ? tcd : w89;  uB[1] = h ? tef : wab;
      uB[2] = h ? wcd : t89;  uB[3] = h ? wef : tab;
      pa0 = __builtin_bit_cast(short8, uA);
      pa1 = __builtin_bit_cast(short8, uB);
    }
    {
      unsigned int w01 = cvtpk(s1[0], s1[1]),  w23 = cvtpk(s1[2], s1[3]);
      unsigned int w45 = cvtpk(s1[4], s1[5]),  w67 = cvtpk(s1[6], s1[7]);
      unsigned int w89 = cvtpk(s1[8], s1[9]),  wab = cvtpk(s1[10], s1[11]);
      unsigned int wcd = cvtpk(s1[12], s1[13]), wef = cvtpk(s1[14], s1[15]);
      unsigned int t01 = (unsigned)__shfl_xor((int)w01, 32);
      unsigned int t23 = (unsigned)__shfl_xor((int)w23, 32);
      unsigned int t45 = (unsigned)__shfl_xor((int)w45, 32);
      unsigned int t67 = (unsigned)__shfl_xor((int)w67, 32);
      unsigned int t89 = (unsigned)__shfl_xor((int)w89, 32);
      unsigned int tab = (unsigned)__shfl_xor((int)wab, 32);
      unsigned int tcd = (unsigned)__shfl_xor((int)wcd, 32);
      unsigned int tef = (unsigned)__shfl_xor((int)wef, 32);
      uint4v uA, uB;
      uA[0] = h ? t45 : w01;  uA[1] = h ? t67 : w23;
      uA[2] = h ? w45 : t01;  uA[3] = h ? w67 : t23;
      uB[0] = h ? tcd : w89;  uB[1] = h ? tef : wab;
      uB[2] = h ? wcd : t89;  uB[3] = h ? wef : tab;
      pa2 = __builtin_bit_cast(short8, uA);
      pa3 = __builtin_bit_cast(short8, uB);
    }
    // ---- PV: 16 MFMA on the pipelined V tile (arrived ~1 tile ago) ----
    __builtin_amdgcn_s_setprio(1);
    acc0 = mfma16(pa0, vf[0][0], acc0);
    acc0 = mfma16(pa1, vf[0][1], acc0);
    acc0 = mfma16(pa2, vf[0][2], acc0);
    acc0 = mfma16(pa3, vf[0][3], acc0);
    acc1 = mfma16(pa0, vf[1][0], acc1);
    acc1 = mfma16(pa1, vf[1][1], acc1);
    acc1 = mfma16(pa2, vf[1][2], acc1);
    acc1 = mfma16(pa3, vf[1][3], acc1);
    acc2 = mfma16(pa0, vf[2][0], acc2);
    acc2 = mfma16(pa1, vf[2][1], acc2);
    acc2 = mfma16(pa2, vf[2][2], acc2);
    acc2 = mfma16(pa3, vf[2][3], acc2);
    acc3 = mfma16(pa0, vf[3][0], acc3);
    acc3 = mfma16(pa1, vf[3][1], acc3);
    acc3 = mfma16(pa2, vf[3][2], acc3);
    acc3 = mfma16(pa3, vf[3][3], acc3);
    __builtin_amdgcn_s_setprio(0);
    // issue V(kt+1) now; latency hides under next tile's QK+softmax+pack
    {
      const int ktv = (kt + 1 < 16) ? kt + 1 : 15;
      loadV(ktv);
    }
  }

  // full-row l (both j-halves); valid for q-row = l31
  const float lfull = l_run + __shfl_xor(l_run, 32);
  if (ch == 0 && h == 0) {
    lpart[(size_t)(s * 4 + b) * 4096 + srow] = lfull;
  }
  // acc register e belongs to q-row (e&3)+8*(e>>2)+4h, not lane:
  // redistribute 1/l from lane-indexed to register-row-indexed.
  const float invo = 1.0f / lfull;
  float invr[16];
#pragma unroll
  for (int e = 0; e < 16; ++e)
    invr[e] = __shfl(invo, (e & 3) + 8 * (e >> 2) + 4 * h);
  {
    const int wv = ((s * 4 + b) * 128 + qw) * 2 + ch;
    unsigned short* dst = Opart + (size_t)wv * 4096 + lane * 8;
    short8 o;
#pragma unroll
    for (int e = 0; e < 8; ++e) o[e] = f32tof16(acc0[e] * invr[e]);
    *(short8*)(dst + 0 * 512) = o;
#pragma unroll
    for (int e = 0; e < 8; ++e) o[e] = f32tof16(acc0[8 + e] * invr[8 + e]);
    *(short8*)(dst + 1 * 512) = o;
#pragma unroll
    for (int e = 0; e < 8; ++e) o[e] = f32tof16(acc1[e] * invr[e]);
    *(short8*)(dst + 2 * 512) = o;
#pragma unroll
    for (int e = 0; e < 8; ++e) o[e] = f32tof16(acc1[8 + e] * invr[8 + e]);
    *(short8*)(dst + 3 * 512) = o;
#pragma unroll
    for (int e = 0; e < 8; ++e) o[e] = f32tof16(acc2[e] * invr[e]);
    *(short8*)(dst + 4 * 512) = o;
#pragma unroll
    for (int e = 0; e < 8; ++e) o[e] = f32tof16(acc2[8 + e] * invr[8 + e]);
    *(short8*)(dst + 5 * 512) = o;
#pragma unroll
    for (int e = 0; e < 8; ++e) o[e] = f32tof16(acc3[e] * invr[e]);
    *(short8*)(dst + 6 * 512) = o;
#pragma unroll
    for (int e = 0; e < 8; ++e) o[e] = f32tof16(acc3[8 + e] * invr[8 + e]);
    *(short8*)(dst + 7 * 512) = o;
  }
}

// ---------------- kernel 4: combine 4 splits + residual ----------------
// O = sum_s (l_s / L) * Obar_s, L = sum l_s (exact under fixed M).
// Opart sub-index for (c, qg): qw = qg>>5; qi = qg&31; h = (qi>>2)&1;
// hi8 = qi>>4; eo = (qi&3)+4*((qi>>3)&1); lane = (c&31)+32h; ct = (c>>5)&3;
// ch = c>>7.
__global__ __launch_bounds__(256) void k_combine(
    const unsigned short* __restrict__ Opart, const float* __restrict__ lpart,
    const float* __restrict__ x, const float* __restrict__ gamma,
    float* __restrict__ out) {
  const int cb = blockIdx.x;
  const int b = cb & 3, qt_ = cb >> 2;
  const int q0 = qt_ * 64;
  const int t = threadIdx.x;
  const int i = t & 63, cg = t >> 6;
  const int qg = q0 + i;

  float lv[4];
#pragma unroll
  for (int s = 0; s < 4; ++s) lv[s] = lpart[(size_t)(s * 4 + b) * 4096 + qg];
  const float L = (lv[0] + lv[1]) + (lv[2] + lv[3]);
  const float giv = gamma[0] / L;
  float sc[4];
#pragma unroll
  for (int s = 0; s < 4; ++s) sc[s] = lv[s] * giv;

  const int qw = qg >> 5, qi = qg & 31;
  const int h = (qi >> 2) & 1;
  const int hi8 = qi >> 4;
  const int eo = (qi & 3) + 4 * ((qi >> 3) & 1);
#pragma unroll 4
  for (int c = cg; c < C_; c += 4) {
    const int ch = c >> 7, ct = (c >> 5) & 3, ln = (c & 31) + 32 * h;
    const size_t sub = (size_t)(ct * 2 + hi8) * 512 + ln * 8 + eo;
    float acc = 0.f;
#pragma unroll
    for (int s = 0; s < 4; ++s) {
      const size_t o =
          (size_t)(((s * 4 + b) * 128 + qw) * 2 + ch) * 4096 + sub;
      acc += sc[s] * (float)__builtin_bit_cast(_Float16, Opart[o]);
    }
    const int g = (b * C_ + c) * N_ + qg;
    out[g] = acc + x[g];
  }
}

// ---------------- launch ----------------
extern "C" void kernel_launch(void* const* d_in, const int* in_sizes, int n_in,
                              void* d_out, int out_size, void* d_ws, size_t ws_size,
                              hipStream_t stream) {
  const float* x     = (const float*)d_in[0];
  const float* Wq    = (const float*)d_in[1];
  const float* bq    = (const float*)d_in[2];
  const float* Wk    = (const float*)d_in[3];
  const float* bk    = (const float*)d_in[4];
  const float* Wv    = (const float*)d_in[5];
  const float* bv    = (const float*)d_in[6];
  const float* gamma = (const float*)d_in[7];
  float* out = (float*)d_out;
  (void)in_sizes; (void)n_in; (void)out_size; (void)ws_size;

  char* ws = (char*)d_ws;
  size_t off = 0;
  auto carve = [&](size_t bytes) -> char* {
    char* p = ws + off;
    off += (bytes + 255) & ~(size_t)255;
    return p;
  };
  unsigned short* xthi = (unsigned short*)carve((size_t)B_ * N_ * C_ * 2);
  unsigned short* xtlo = (unsigned short*)carve((size_t)B_ * N_ * C_ * 2);
  unsigned short* wqh  = (unsigned short*)carve(32 * 256 * 2);
  unsigned short* wql  = (unsigned short*)carve(32 * 256 * 2);
  unsigned short* wkh  = (unsigned short*)carve(32 * 256 * 2);
  unsigned short* wkl  = (unsigned short*)carve(32 * 256 * 2);
  unsigned short* wvh  = (unsigned short*)carve(256 * 256 * 2);
  unsigned short* wvl  = (unsigned short*)carve(256 * 256 * 2);
  unsigned short* qhg  = (unsigned short*)carve((size_t)B_ * N_ * CQK * 2);
  unsigned short* qlg  = (unsigned short*)carve((size_t)B_ * N_ * CQK * 2);
  unsigned short* kfrh = (unsigned short*)carve((size_t)B_ * N_ * CQK * 2);
  unsigned short* kfrl = (unsigned short*)carve((size_t)B_ * N_ * CQK * 2);
  unsigned short* vfr  = (unsigned short*)carve((size_t)B_ * C_ * N_ * 2);
  unsigned short* Opart = (unsigned short*)carve((size_t)4096 * 4096 * 2);  // f16
  float* lpart = (float*)carve((size_t)16 * 4096 * 4);

  k_prep<<<1344, 256, 0, stream>>>(x, xthi, xtlo, Wq, Wk, Wv,
                                   wqh, wql, wkh, wkl, wvh, wvl);
  k_proj<<<dim3(64, 5, B_), 256, 0, stream>>>(wqh, wql, wkh, wkl, wvh, wvl,
                                              xthi, xtlo, bq, bk, bv,
                                              qhg, qlg, kfrh, kfrl, vfr);
  k_flash<<<1024, 256, 0, stream>>>(qhg, qlg, kfrh, kfrl, vfr, Opart, lpart);
  k_combine<<<256, 256, 0, stream>>>(Opart, lpart, x, gamma, out);
}

// Round 13
// 175.813 us; speedup vs baseline: 1.1094x; 1.1094x over previous
//
#include <hip/hip_runtime.h>

// SelfAttention (B=4, C=256, H=W=64): fused projections + merged-wave flash.
// Round 16: r15's bench died on container acquisition (infra, not kernel) --
// resubmitting unchanged after a safety audit (no divergent barriers, LDS
// within bounds, exchange layout re-derived). Theory unchanged:
// r13's VALUBusy 40% (~37us of issue) is dominated by exp2/pack work that is
// FULLY DUPLICATED across the two ch-waves of each qw-pair. This round:
// symmetric pairwise dedup: each wave computes only its own 32-j half of
// QK+softmax+pack (6 MFMA, 16 exp2), exchanges P-fragments + partial-l with
// its partner wave through a bank-conflict-free b32 LDS buffer (one extra
// barrier/tile; waves are symmetric -> no producer/consumer convoy). PV
// unchanged (16 MFMA on all 4 j-fragments). K regs/loads halve too.
// Everything else = r13: fragment-packed K/V, phase-lock, fixed-M exp2
// softmax, split-K x4 (1024 blocks x 4 waves), normalized f16 partials + l,
// exact 4-way combine.

#define B_ 4
#define C_ 256
#define N_ 4096
#define CQK 32
#define LOG2E 1.44269504088896340736f

typedef __attribute__((ext_vector_type(8))) short short8;
typedef __attribute__((ext_vector_type(4))) short short4v;
typedef __attribute__((ext_vector_type(4))) unsigned int uint4v;
typedef __attribute__((ext_vector_type(16))) float f32x16;
typedef __attribute__((ext_vector_type(4))) float f32x4;

__device__ __forceinline__ unsigned short f2bf(float f) {
  unsigned int u = __builtin_bit_cast(unsigned int, f);
  u = (u + 0x7fffu + ((u >> 16) & 1u)) >> 16;  // RNE
  return (unsigned short)u;
}
__device__ __forceinline__ float bf2f(unsigned short s) {
  unsigned int u = ((unsigned int)s) << 16;
  return __builtin_bit_cast(float, u);
}
__device__ __forceinline__ short f32tof16(float f) {
  const _Float16 hf = (_Float16)f;
  return __builtin_bit_cast(short, hf);
}
// pack two f32 -> two bf16 (RNE), one instruction
__device__ __forceinline__ unsigned int cvtpk(float lo, float hi) {
  unsigned int r;
  asm("v_cvt_pk_bf16_f32 %0, %1, %2" : "=v"(r) : "v"(lo), "v"(hi));
  return r;
}
__device__ __forceinline__ f32x16 mfma16(short8 a, short8 b, f32x16 c) {
  return __builtin_amdgcn_mfma_f32_32x32x16_bf16(a, b, c, 0, 0, 0);
}
// swizzled element index into bf16 LDS tiles (16B granules XORed by row)
__device__ __forceinline__ int swz64(int row, int col) {  // rows of 64 bf16
  return row * 64 + ((((col >> 3) ^ row) & 7) << 3) + (col & 7);
}

#define WAITCNT(s) asm volatile("s_waitcnt " s ::: "memory")

// ---------------- kernel 1: prep (x transpose+split, weight splits) ----------
__global__ __launch_bounds__(256) void k_prep(
    const float* __restrict__ x, unsigned short* __restrict__ xthi,
    unsigned short* __restrict__ xtlo,
    const float* __restrict__ Wq, const float* __restrict__ Wk,
    const float* __restrict__ Wv,
    unsigned short* __restrict__ wqh, unsigned short* __restrict__ wql,
    unsigned short* __restrict__ wkh, unsigned short* __restrict__ wkl,
    unsigned short* __restrict__ wvh, unsigned short* __restrict__ wvl) {
  __shared__ __align__(16) float tile[64 * 65];
  const int bi = blockIdx.x;
  const int t = threadIdx.x;
  if (bi < 1024) {
    const int it = bi & 63, ct = (bi >> 6) & 3, b = bi >> 8;
    const int i0 = it * 64, c0 = ct * 64;
    {
      const int i = t & 63, cb = t >> 6;
#pragma unroll
      for (int z = 0; z < 16; ++z) {
        const int c = z * 4 + cb;
        tile[i * 65 + c] = x[(b * C_ + c0 + c) * N_ + i0 + i];
      }
    }
    __syncthreads();
    {
      const int ii = t >> 2, p = t & 3;
      short8 h0, h1, l0, l1;
#pragma unroll
      for (int e = 0; e < 16; ++e) {
        const float f = tile[ii * 65 + p * 16 + e];
        const unsigned short hb = f2bf(f);
        const unsigned short lb = f2bf(f - bf2f(hb));
        if (e < 8) { h0[e] = (short)hb; l0[e] = (short)lb; }
        else       { h1[e - 8] = (short)hb; l1[e - 8] = (short)lb; }
      }
      const int base = (b * N_ + i0 + ii) * C_ + c0 + p * 16;
      *(short8*)(xthi + base) = h0;
      *(short8*)(xthi + base + 8) = h1;
      *(short8*)(xtlo + base) = l0;
      *(short8*)(xtlo + base + 8) = l1;
    }
  } else {
    const int e = (bi - 1024) * 256 + t;  // < 81920
    const float* src; unsigned short *hi, *lo; int idx;
    if (e < 8192)        { src = Wq; hi = wqh; lo = wql; idx = e; }
    else if (e < 16384)  { src = Wk; hi = wkh; lo = wkl; idx = e - 8192; }
    else                 { src = Wv; hi = wvh; lo = wvl; idx = e - 16384; }
    float f = src[idx];
    if (e < 8192) f *= LOG2E;  // log2-domain scores: fold log2(e) into Wq
    const unsigned short h = f2bf(f);
    hi[idx] = h;
    lo[idx] = f2bf(f - bf2f(h));
  }
}

// ---------------- kernel 2: fused q/k/v projection GEMM ----------------
// q written [B][N][32] hi/lo (unchanged). K and V written FRAGMENT-PACKED:
// kfr[((b*128 + j32t)*2 + kk)*64 + (jl + 32*h)]*8  holds K[j32t*32+jl][kk*16+h*8+..]
// vfr[(b*64+jt)*16384 + ct*2048 + sl*512 + (cl+32*hh)*8 + e8]
//    holds V[ct*32+cl][jt*64 + sl*16 + hh*8 + e8]
__global__ __launch_bounds__(256) void k_proj(
    const unsigned short* __restrict__ wqh, const unsigned short* __restrict__ wql,
    const unsigned short* __restrict__ wkh, const unsigned short* __restrict__ wkl,
    const unsigned short* __restrict__ wvh, const unsigned short* __restrict__ wvl,
    const unsigned short* __restrict__ xthi, const unsigned short* __restrict__ xtlo,
    const float* __restrict__ bq, const float* __restrict__ bk,
    const float* __restrict__ bv,
    unsigned short* __restrict__ qhg, unsigned short* __restrict__ qlg,
    unsigned short* __restrict__ kfrh, unsigned short* __restrict__ kfrl,
    unsigned short* __restrict__ vfr) {
  __shared__ __align__(16) char sm[33792];
  unsigned short* awh = (unsigned short*)sm;       // [64][64] W hi (swizzled)
  unsigned short* awl = awh + 4096;
  unsigned short* bxh = awl + 4096;                // [64][64] x^T hi
  unsigned short* bxl = bxh + 4096;
  float* qt = (float*)sm;                          // epilogue reuse: [64][65] f32

  const int it = blockIdx.x, ot = blockIdx.y, b = blockIdx.z;
  const int i0 = it * 64, o0 = ot * 64;
  const int t = threadIdx.x, lane = t & 63, w = t >> 6, h = lane >> 5;
  const int mb = w >> 1, nb = w & 1;
  const int srow = t >> 2, sp = t & 3;

  const int og = o0 + srow;
  const unsigned short *wh, *wl;
  if (og < 32)      { wh = wqh + og * C_;        wl = wql + og * C_; }
  else if (og < 64) { wh = wkh + (og - 32) * C_; wl = wkl + (og - 32) * C_; }
  else              { wh = wvh + (og - 64) * C_; wl = wvl + (og - 64) * C_; }
  const unsigned short* xh = xthi + (b * N_ + i0 + srow) * C_;
  const unsigned short* xl = xtlo + (b * N_ + i0 + srow) * C_;

  f32x16 acc;
#pragma unroll
  for (int e = 0; e < 16; ++e) acc[e] = 0.f;
  const int m = 32 * mb + (lane & 31);
  const int n = 32 * nb + (lane & 31);

  for (int kt = 0; kt < 4; ++kt) {
    const int cb = kt * 64 + sp * 16;
    *(short8*)&awh[swz64(srow, sp * 16)]     = *(const short8*)(wh + cb);
    *(short8*)&awh[swz64(srow, sp * 16 + 8)] = *(const short8*)(wh + cb + 8);
    *(short8*)&awl[swz64(srow, sp * 16)]     = *(const short8*)(wl + cb);
    *(short8*)&awl[swz64(srow, sp * 16 + 8)] = *(const short8*)(wl + cb + 8);
    *(short8*)&bxh[swz64(srow, sp * 16)]     = *(const short8*)(xh + cb);
    *(short8*)&bxh[swz64(srow, sp * 16 + 8)] = *(const short8*)(xh + cb + 8);
    *(short8*)&bxl[swz64(srow, sp * 16)]     = *(const short8*)(xl + cb);
    *(short8*)&bxl[swz64(srow, sp * 16 + 8)] = *(const short8*)(xl + cb + 8);
    __syncthreads();
#pragma unroll
    for (int kk = 0; kk < 4; ++kk) {
      const int kb = kk * 16 + h * 8;
      const short8 ah  = *(const short8*)&awh[swz64(m, kb)];
      const short8 al2 = *(const short8*)&awl[swz64(m, kb)];
      const short8 bh  = *(const short8*)&bxh[swz64(n, kb)];
      const short8 bl2 = *(const short8*)&bxl[swz64(n, kb)];
      acc = mfma16(ah, bh, acc);   // hi*hi
      acc = mfma16(ah, bl2, acc);  // hi*lo
      acc = mfma16(al2, bh, acc);  // lo*hi
    }
    __syncthreads();
  }

  if (ot > 0) {  // v epilogue: fragment-packed bf16 scatter store
    // thread owns (oc = o0-64+32*mb+rr, j = i0+n); it == jt, n == jl
    const int vbase = (b * 64 + it) * 16384 + (2 * (ot - 1) + mb) * 2048 +
                      (n >> 4) * 512 + 256 * ((n >> 3) & 1) + (n & 7);
#pragma unroll
    for (int e = 0; e < 16; ++e) {
      const int rr = (e & 3) + 8 * (e >> 2) + 4 * h;
      const int oc = o0 - 64 + 32 * mb + rr;
      vfr[vbase + rr * 8] = f2bf(acc[e] + bv[oc]);
    }
  } else {  // q/k epilogue: LDS transpose -> q [B][N][32]; K fragment-packed
#pragma unroll
    for (int e = 0; e < 16; ++e) {
      const int r = 32 * mb + (e & 3) + 8 * (e >> 2) + 4 * h;
      const float bias = (r < 32) ? bq[r] * LOG2E : bk[r - 32];
      qt[r * 65 + n] = acc[e] + bias;
    }
    __syncthreads();
    const int ii = t >> 2;
    short8 hv0, hv1, lv0, lv1;
#pragma unroll
    for (int e = 0; e < 16; ++e) {
      const float f = qt[(sp * 16 + e) * 65 + ii];
      const unsigned short hb = f2bf(f);
      const unsigned short lb = f2bf(f - bf2f(hb));
      if (e < 8) { hv0[e] = (short)hb; lv0[e] = (short)lb; }
      else       { hv1[e - 8] = (short)hb; lv1[e - 8] = (short)lb; }
    }
    if (sp < 2) {
      const int base = (b * N_ + i0 + ii) * CQK + sp * 16;
      *(short8*)(qhg + base) = hv0; *(short8*)(qhg + base + 8) = hv1;
      *(short8*)(qlg + base) = lv0; *(short8*)(qlg + base + 8) = lv1;
    } else {
      // key = i0+ii; hv0 = cqk[kk*16..+8] (h=0), hv1 = cqk[kk*16+8..] (h=1)
      const int key = i0 + ii;
      const int j32t = key >> 5, jl = key & 31;
      const int kk = sp - 2;
      const size_t kb2 = ((size_t)(b * 128 + j32t) * 2 + kk) * 512;
      *(short8*)(kfrh + kb2 + jl * 8) = hv0;
      *(short8*)(kfrh + kb2 + (jl + 32) * 8) = hv1;
      *(short8*)(kfrl + kb2 + jl * 8) = lv0;
      *(short8*)(kfrl + kb2 + (jl + 32) * 8) = lv1;
    }
  }
}

// ---------------- kernel 3: merged-wave flash, fixed-M, pair-dedup ----------
// 1024 blocks x 256 thr (4 waves). xs = blk&7 = b*2+s_hi (XCD-pinned);
// gl = blk>>3: s = (xs&1)*2 + (gl&1); widx = (gl>>1)*4+w: qw=widx>>1, ch=widx&1.
// Waves {0,1} and {2,3} are qw-pairs. Each wave computes only its OWN 32-j
// half of QK (6 MFMA) + exp2 (16) + pack (2 frags), exchanges fragments and
// per-lane partial-l with its partner through LDS (b32 conflict-free layout),
// then PV = 16 MFMA over all 4 j-fragments. V loaded in two halves inside PV
// (r13 style). Fixed M=0, log2 domain. Opart: [wave 4096][slot 8][lane][8 f16].
__global__ __launch_bounds__(256, 2) void k_flash(
    const unsigned short* __restrict__ qhg, const unsigned short* __restrict__ qlg,
    const unsigned short* __restrict__ kfrh, const unsigned short* __restrict__ kfrl,
    const unsigned short* __restrict__ vfr,
    unsigned short* __restrict__ Opart, float* __restrict__ lpart) {
  __shared__ __align__(16) char sm[9216];
  // pa exchange: uint idx = w*512 + dw*64 + lane (dw stride 256B -> b32 clean)
  // l exchange: float at sm+8192, idx = w*64 + lane

  const int blk = blockIdx.x;
  const int xs = blk & 7;          // XCD-pinned (b, s_hi)
  const int b = xs >> 1;
  const int gl = blk >> 3;         // 0..127
  const int s = (xs & 1) * 2 + (gl & 1);
  const int t = threadIdx.x, lane = t & 63, w = t >> 6, h = lane >> 5;
  const int l31 = lane & 31;
  const int widx = (gl >> 1) * 4 + w;  // 0..255
  const int qw = widx >> 1, ch = widx & 1;
  const int srow = qw * 32 + l31;  // q row of this lane (QK layout)

  unsigned int* paown = (unsigned int*)sm + w * 512 + lane;
  unsigned int* papar = (unsigned int*)sm + (w ^ 1) * 512 + lane;
  float* tsown = (float*)(sm + 8192) + w * 64 + lane;
  float* tspar = (float*)(sm + 8192) + (w ^ 1) * 64 + lane;

  // Q fragments (persistent): B-operand for QK, lane = q
  short8 qfh[2], qfl[2];
  {
    const unsigned short* qph = qhg + (size_t)(b * N_ + srow) * CQK + h * 8;
    const unsigned short* qpl = qlg + (size_t)(b * N_ + srow) * CQK + h * 8;
#pragma unroll
    for (int kk = 0; kk < 2; ++kk) {
      qfh[kk] = *(const short8*)(qph + kk * 16);
      qfl[kk] = *(const short8*)(qpl + kk * 16);
    }
  }
  // K fragments: packed blocks of 512 shorts; OWN half only (j32t = tau*2+ch)
  const unsigned short* kbh = kfrh + (size_t)(b * 128 + s * 32) * 1024 + lane * 8;
  const unsigned short* kbl = kfrl + (size_t)(b * 128 + s * 32) * 1024 + lane * 8;
  short8 kfh[2], kfl[2];
  auto loadK = [&](int tau) {
#pragma unroll
    for (int kk = 0; kk < 2; ++kk) {
      const int off = ((tau * 2 + ch) * 2 + kk) * 512;
      kfh[kk] = *(const short8*)(kbh + off);
      kfl[kk] = *(const short8*)(kbl + off);
    }
  };
  loadK(0);
  // V fragments: packed; per (tile, ct, sl) a contiguous 1KB wave-load
  const unsigned short* vbase =
      vfr + (size_t)(b * 64 + s * 16) * 16384 + (ch * 4) * 2048 + lane * 8;

  f32x16 acc0, acc1, acc2, acc3;
#pragma unroll
  for (int e = 0; e < 16; ++e) {
    acc0[e] = 0.f; acc1[e] = 0.f; acc2[e] = 0.f; acc3[e] = 0.f;
  }
  float l_run = 0.f;  // lane-local partial (own+partner subsets); shfl at end

  for (int kt = 0; kt < 16; ++kt) {
    // top barrier: WAR safety (partner reads of our pa slot drained by each
    // wave's own lgkmcnt before arriving) + phase-lock for L1 stream dedup
    WAITCNT("lgkmcnt(0)");
    __builtin_amdgcn_s_barrier();
    // QK own half: S^T 32x32, lane = q, regs = j pattern (e&3)+8*(e>>2)+4h
    f32x16 sS;
#pragma unroll
    for (int e = 0; e < 16; ++e) sS[e] = 0.f;
    __builtin_amdgcn_s_setprio(1);
#pragma unroll
    for (int kk = 0; kk < 2; ++kk) {
      sS = mfma16(kfh[kk], qfh[kk], sS);
      sS = mfma16(kfh[kk], qfl[kk], sS);
      sS = mfma16(kfl[kk], qfh[kk], sS);
    }
    __builtin_amdgcn_s_setprio(0);
    if (kt + 1 < 16) loadK(kt + 1);  // prefetch next K (own half)
    // ---- fixed-M softmax: P = exp2(S) (log2 domain), no max chain ----
#pragma unroll
    for (int e = 0; e < 16; ++e) sS[e] = __builtin_exp2f(sS[e]);
    float ts;
    {
      float t4[4];
#pragma unroll
      for (int i2 = 0; i2 < 4; ++i2)
        t4[i2] = (sS[4 * i2] + sS[4 * i2 + 1]) + (sS[4 * i2 + 2] + sS[4 * i2 + 3]);
      ts = (t4[0] + t4[1]) + (t4[2] + t4[3]);
    }
    // ---- pack own half -> 2 fragments (8 uints), verified layout ----
    unsigned int u0, u1, u2, u3, u4, u5, u6, u7;
    {
      unsigned int w01 = cvtpk(sS[0], sS[1]),  w23 = cvtpk(sS[2], sS[3]);
      unsigned int w45 = cvtpk(sS[4], sS[5]),  w67 = cvtpk(sS[6], sS[7]);
      unsigned int w89 = cvtpk(sS[8], sS[9]),  wab = cvtpk(sS[10], sS[11]);
      unsigned int wcd = cvtpk(sS[12], sS[13]), wef = cvtpk(sS[14], sS[15]);
      unsigned int t01 = (unsigned)__shfl_xor((int)w01, 32);
      unsigned int t23 = (unsigned)__shfl_xor((int)w23, 32);
      unsigned int t45 = (unsigned)__shfl_xor((int)w45, 32);
      unsigned int t67 = (unsigned)__shfl_xor((int)w67, 32);
      unsigned int t89 = (unsigned)__shfl_xor((int)w89, 32);
      unsigned int tab = (unsigned)__shfl_xor((int)wab, 32);
      unsigned int tcd = (unsigned)__shfl_xor((int)wcd, 32);
      unsigned int tef = (unsigned)__shfl_xor((int)wef, 32);
      u0 = h ? t45 : w01;  u1 = h ? t67 : w23;
      u2 = h ? w45 : t01;  u3 = h ? w67 : t23;
      u4 = h ? tcd : w89;  u5 = h ? tef : wab;
      u6 = h ? wcd : t89;  u7 = h ? wef : tab;
    }
    // ---- exchange with partner wave ----
    paown[0 * 64] = u0;  paown[1 * 64] = u1;
    paown[2 * 64] = u2;  paown[3 * 64] = u3;
    paown[4 * 64] = u4;  paown[5 * 64] = u5;
    paown[6 * 64] = u6;  paown[7 * 64] = u7;
    *tsown = ts;
    WAITCNT("lgkmcnt(0)");
    __builtin_amdgcn_s_barrier();
    unsigned int p0 = papar[0 * 64], p1 = papar[1 * 64];
    unsigned int p2 = papar[2 * 64], p3 = papar[3 * 64];
    unsigned int p4 = papar[4 * 64], p5 = papar[5 * 64];
    unsigned int p6 = papar[6 * 64], p7 = papar[7 * 64];
    l_run += ts + *tspar;
    // assemble j-ordered fragments: jf[i] pairs with V k-slice i
    short8 jf0, jf1, jf2, jf3;
    {
      uint4v A0 = {u0, u1, u2, u3}, A1 = {u4, u5, u6, u7};
      uint4v P0 = {p0, p1, p2, p3}, P1 = {p4, p5, p6, p7};
      jf0 = __builtin_bit_cast(short8, ch ? P0 : A0);
      jf1 = __builtin_bit_cast(short8, ch ? P1 : A1);
      jf2 = __builtin_bit_cast(short8, ch ? A0 : P0);
      jf3 = __builtin_bit_cast(short8, ch ? A1 : P1);
    }
    // ---- PV in two halves (V loads contiguous, r13 style) ----
    {
      short8 vfA[4], vfB[4];
#pragma unroll
      for (int sl = 0; sl < 4; ++sl) {
        vfA[sl] = *(const short8*)(vbase + kt * 16384 + 0 * 2048 + sl * 512);
        vfB[sl] = *(const short8*)(vbase + kt * 16384 + 1 * 2048 + sl * 512);
      }
      __builtin_amdgcn_s_setprio(1);
      acc0 = mfma16(jf0, vfA[0], acc0);
      acc0 = mfma16(jf1, vfA[1], acc0);
      acc0 = mfma16(jf2, vfA[2], acc0);
      acc0 = mfma16(jf3, vfA[3], acc0);
      acc1 = mfma16(jf0, vfB[0], acc1);
      acc1 = mfma16(jf1, vfB[1], acc1);
      acc1 = mfma16(jf2, vfB[2], acc1);
      acc1 = mfma16(jf3, vfB[3], acc1);
      __builtin_amdgcn_s_setprio(0);
    }
    {
      short8 vfA[4], vfB[4];
#pragma unroll
      for (int sl = 0; sl < 4; ++sl) {
        vfA[sl] = *(const short8*)(vbase + kt * 16384 + 2 * 2048 + sl * 512);
        vfB[sl] = *(const short8*)(vbase + kt * 16384 + 3 * 2048 + sl * 512);
      }
      __builtin_amdgcn_s_setprio(1);
      acc2 = mfma16(jf0, vfA[0], acc2);
      acc2 = mfma16(jf1, vfA[1], acc2);
      acc2 = mfma16(jf2, vfA[2], acc2);
      acc2 = mfma16(jf3, vfA[3], acc2);
      acc3 = mfma16(jf0, vfB[0], acc3);
      acc3 = mfma16(jf1, vfB[1], acc3);
      acc3 = mfma16(jf2, vfB[2], acc3);
      acc3 = mfma16(jf3, vfB[3], acc3);
      __builtin_amdgcn_s_setprio(0);
    }
  }

  // full-row l (lane's subsets + lane^32's subsets); valid for q-row = l31
  const float lfull = l_run + __shfl_xor(l_run, 32);
  if (ch == 0 && h == 0) {
    lpart[(size_t)(s * 4 + b) * 4096 + srow] = lfull;
  }
  // acc register e belongs to q-row (e&3)+8*(e>>2)+4h, not lane:
  // redistribute 1/l from lane-indexed to register-row-indexed.
  const float invo = 1.0f / lfull;
  float invr[16];
#pragma unroll
  for (int e = 0; e < 16; ++e)
    invr[e] = __shfl(invo, (e & 3) + 8 * (e >> 2) + 4 * h);
  {
    const int wv = ((s * 4 + b) * 128 + qw) * 2 + ch;
    unsigned short* dst = Opart + (size_t)wv * 4096 + lane * 8;
    short8 o;
#pragma unroll
    for (int e = 0; e < 8; ++e) o[e] = f32tof16(acc0[e] * invr[e]);
    *(short8*)(dst + 0 * 512) = o;
#pragma unroll
    for (int e = 0; e < 8; ++e) o[e] = f32tof16(acc0[8 + e] * invr[8 + e]);
    *(short8*)(dst + 1 * 512) = o;
#pragma unroll
    for (int e = 0; e < 8; ++e) o[e] = f32tof16(acc1[e] * invr[e]);
    *(short8*)(dst + 2 * 512) = o;
#pragma unroll
    for (int e = 0; e < 8; ++e) o[e] = f32tof16(acc1[8 + e] * invr[8 + e]);
    *(short8*)(dst + 3 * 512) = o;
#pragma unroll
    for (int e = 0; e < 8; ++e) o[e] = f32tof16(acc2[e] * invr[e]);
    *(short8*)(dst + 4 * 512) = o;
#pragma unroll
    for (int e = 0; e < 8; ++e) o[e] = f32tof16(acc2[8 + e] * invr[8 + e]);
    *(short8*)(dst + 5 * 512) = o;
#pragma unroll
    for (int e = 0; e < 8; ++e) o[e] = f32tof16(acc3[e] * invr[e]);
    *(short8*)(dst + 6 * 512) = o;
#pragma unroll
    for (int e = 0; e < 8; ++e) o[e] = f32tof16(acc3[8 + e] * invr[8 + e]);
    *(short8*)(dst + 7 * 512) = o;
  }
}

// ---------------- kernel 4: combine 4 splits + residual ----------------
// O = sum_s (l_s / L) * Obar_s, L = sum l_s (exact under fixed M).
// Opart sub-index for (c, qg): qw = qg>>5; qi = qg&31; h = (qi>>2)&1;
// hi8 = qi>>4; eo = (qi&3)+4*((qi>>3)&1); lane = (c&31)+32h; ct = (c>>5)&3;
// ch = c>>7.
__global__ __launch_bounds__(256) void k_combine(
    const unsigned short* __restrict__ Opart, const float* __restrict__ lpart,
    const float* __restrict__ x, const float* __restrict__ gamma,
    float* __restrict__ out) {
  const int cb = blockIdx.x;
  const int b = cb & 3, qt_ = cb >> 2;
  const int q0 = qt_ * 64;
  const int t = threadIdx.x;
  const int i = t & 63, cg = t >> 6;
  const int qg = q0 + i;

  float lv[4];
#pragma unroll
  for (int s = 0; s < 4; ++s) lv[s] = lpart[(size_t)(s * 4 + b) * 4096 + qg];
  const float L = (lv[0] + lv[1]) + (lv[2] + lv[3]);
  const float giv = gamma[0] / L;
  float sc[4];
#pragma unroll
  for (int s = 0; s < 4; ++s) sc[s] = lv[s] * giv;

  const int qw = qg >> 5, qi = qg & 31;
  const int h = (qi >> 2) & 1;
  const int hi8 = qi >> 4;
  const int eo = (qi & 3) + 4 * ((qi >> 3) & 1);
#pragma unroll 4
  for (int c = cg; c < C_; c += 4) {
    const int ch = c >> 7, ct = (c >> 5) & 3, ln = (c & 31) + 32 * h;
    const size_t sub = (size_t)(ct * 2 + hi8) * 512 + ln * 8 + eo;
    float acc = 0.f;
#pragma unroll
    for (int s = 0; s < 4; ++s) {
      const size_t o =
          (size_t)(((s * 4 + b) * 128 + qw) * 2 + ch) * 4096 + sub;
      acc += sc[s] * (float)__builtin_bit_cast(_Float16, Opart[o]);
    }
    const int g = (b * C_ + c) * N_ + qg;
    out[g] = acc + x[g];
  }
}

// ---------------- launch ----------------
extern "C" void kernel_launch(void* const* d_in, const int* in_sizes, int n_in,
                              void* d_out, int out_size, void* d_ws, size_t ws_size,
                              hipStream_t stream) {
  const float* x     = (const float*)d_in[0];
  const float* Wq    = (const float*)d_in[1];
  const float* bq    = (const float*)d_in[2];
  const float* Wk    = (const float*)d_in[3];
  const float* bk    = (const float*)d_in[4];
  const float* Wv    = (const float*)d_in[5];
  const float* bv    = (const float*)d_in[6];
  const float* gamma = (const float*)d_in[7];
  float* out = (float*)d_out;
  (void)in_sizes; (void)n_in; (void)out_size; (void)ws_size;

  char* ws = (char*)d_ws;
  size_t off = 0;
  auto carve = [&](size_t bytes) -> char* {
    char* p = ws + off;
    off += (bytes + 255) & ~(size_t)255;
    return p;
  };
  unsigned short* xthi = (unsigned short*)carve((size_t)B_ * N_ * C_ * 2);
  unsigned short* xtlo = (unsigned short*)carve((size_t)B_ * N_ * C_ * 2);
  unsigned short* wqh  = (unsigned short*)carve(32 * 256 * 2);
  unsigned short* wql  = (unsigned short*)carve(32 * 256 * 2);
  unsigned short* wkh  = (unsigned short*)carve(32 * 256 * 2);
  unsigned short* wkl  = (unsigned short*)carve(32 * 256 * 2);
  unsigned short* wvh  = (unsigned short*)carve(256 * 256 * 2);
  unsigned short* wvl  = (unsigned short*)carve(256 * 256 * 2);
  unsigned short* qhg  = (unsigned short*)carve((size_t)B_ * N_ * CQK * 2);
  unsigned short* qlg  = (unsigned short*)carve((size_t)B_ * N_ * CQK * 2);
  unsigned short* kfrh = (unsigned short*)carve((size_t)B_ * N_ * CQK * 2);
  unsigned short* kfrl = (unsigned short*)carve((size_t)B_ * N_ * CQK * 2);
  unsigned short* vfr  = (unsigned short*)carve((size_t)B_ * C_ * N_ * 2);
  unsigned short* Opart = (unsigned short*)carve((size_t)4096 * 4096 * 2);  // f16
  float* lpart = (float*)carve((size_t)16 * 4096 * 4);

  k_prep<<<1344, 256, 0, stream>>>(x, xthi, xtlo, Wq, Wk, Wv,
                                   wqh, wql, wkh, wkl, wvh, wvl);
  k_proj<<<dim3(64, 5, B_), 256, 0, stream>>>(wqh, wql, wkh, wkl, wvh, wvl,
                                              xthi, xtlo, bq, bk, bv,
                                              qhg, qlg, kfrh, kfrl, vfr);
  k_flash<<<1024, 256, 0, stream>>>(qhg, qlg, kfrh, kfrl, vfr, Opart, lpart);
  k_combine<<<256, 256, 0, stream>>>(Opart, lpart, x, gamma, out);
}